// Round 3
// baseline (323.978 us; speedup 1.0000x reference)
//
#include <hip/hip_runtime.h>

typedef __attribute__((ext_vector_type(4))) float f32x4;
typedef __attribute__((ext_vector_type(8))) short s16x8;
typedef unsigned short u16;

#define NV 8192
#define NE 16384
#define MTOT 24576
#define DD 128
#define HH 256

#define BIGSPLIT 8
#define BKS 64
#define KRANGE (NE / BIGSPLIT)   // 2048
#define NSTEPB (KRANGE / BKS)    // 32
#define HPITCH 264               // u16 pitch for h in LDS (528B = 132 dw ≡ 4 mod 32 -> 2-way free)

// ---------- helpers ----------
__device__ __forceinline__ u16 f2bf(float f) {
    unsigned u = __builtin_bit_cast(unsigned, f);
    u += 0x7fffu + ((u >> 16) & 1u);   // RTNE
    return (u16)(u >> 16);
}

__device__ __forceinline__ float wsum(float v) {
#pragma unroll
    for (int o = 32; o > 0; o >>= 1) v += __shfl_xor(v, o, 64);
    return v;
}

__device__ __forceinline__ f32x4 ntload4(const float* p) {
    return __builtin_nontemporal_load((const f32x4*)p);
}

// ---------- prep: PE tables + all weight packs in ONE launch ----------
// pack: src fp32 [K][C]; (k,n) -> dst[(((k>>5)*(C/16)+(n>>4))*64 + (n&15) + (((k&31)>>3)<<4))*8 + (k&7)]
__global__ void k_prep(float* __restrict__ pe1, float* __restrict__ pe2,
                       const float* __restrict__ w11, u16* __restrict__ d11,
                       const float* __restrict__ w12, u16* __restrict__ d12,
                       const float* __restrict__ w21, u16* __restrict__ d21,
                       const float* __restrict__ w22, u16* __restrict__ d22,
                       const float* __restrict__ w31, u16* __restrict__ d31,
                       const float* __restrict__ w32, u16* __restrict__ d32) {
    int b = blockIdx.x, t = threadIdx.x;
    if (b == 0) {
        const float c = logf(10000.0f) / 64.0f;
        for (int idx = t; idx < 9 * DD; idx += 256) {
            int p = idx / DD, col = idx % DD, j = col >> 1;
            float a = (float)p * expf(-(float)j * c);
            pe1[idx] = (col & 1) ? cosf(a) : sinf(a);
        }
        for (int idx = t; idx < 2 * DD; idx += 256) {
            int p = idx / DD, col = idx % DD, j = col >> 1;
            float a = (float)p * expf(-(float)j * c);
            pe2[idx] = (col & 1) ? cosf(a) : sinf(a);
        }
        return;
    }
    b -= 1;
    const float* src; u16* dst; int C, base;
    if (b < 256)      { src = w11; dst = d11; C = 256; base = 0; }
    else if (b < 384) { src = w12; dst = d12; C = 128; base = 256; }
    else if (b < 640) { src = w21; dst = d21; C = 256; base = 384; }
    else if (b < 768) { src = w22; dst = d22; C = 128; base = 640; }
    else if (b < 896) { src = w31; dst = d31; C = 256; base = 768; }
    else              { src = w32; dst = d32; C = 128; base = 896; }
    int i = (b - base) * 256 + t;
    int k = i / C, n = i % C;
    size_t o = (((size_t)(k >> 5) * (C >> 4) + (n >> 4)) * 64 + (n & 15) + (((k & 31) >> 3) << 4)) * 8 + (k & 7);
    dst[o] = f2bf(src[i]);
}

// ---------- LN + concat(PE) stage 1 ----------
__global__ __launch_bounds__(256) void k_ln_cat1(const float* __restrict__ xv, const float* __restrict__ xe,
                                                 const int* __restrict__ orders, const float* __restrict__ pe1,
                                                 const float* __restrict__ g, const float* __restrict__ bn,
                                                 u16* __restrict__ cat) {
    int wave = threadIdx.x >> 6, lane = threadIdx.x & 63;
    int row = blockIdx.x * 4 + wave;
    const float* x = (row < NV) ? xv + (size_t)row * DD : xe + (size_t)(row - NV) * DD;
    float2 v = *(const float2*)(x + lane * 2);
    float mu = wsum(v.x + v.y) * (1.0f / DD);
    float var = wsum(v.x * v.x + v.y * v.y) * (1.0f / DD) - mu * mu;
    float rs = rsqrtf(var + 1e-5f);
    int c = lane * 2;
    u16* crow = cat + (size_t)row * 256;
    crow[c]     = f2bf((v.x - mu) * rs * g[c]     + bn[c]);
    crow[c + 1] = f2bf((v.y - mu) * rs * g[c + 1] + bn[c + 1]);
    const float* pr = pe1 + (size_t)((row < NV) ? 1 : orders[row - NV]) * DD;
    crow[DD + c]     = f2bf(pr[c]);
    crow[DD + c + 1] = f2bf(pr[c + 1]);
}

// ---------- fused MLP building blocks ----------
// fc1: A (global, row-major K1) @ W1p (packed) + b1 -> relu -> hlds [64][HPITCH]
template <int K1>
__device__ __forceinline__ void mlp_fc1(const u16* __restrict__ A, const u16* __restrict__ W1p,
                                        const float* __restrict__ b1, int rowb_blk, int lane, int wave,
                                        u16* __restrict__ hlds) {
    int rowb = rowb_blk + wave * 16;
    f32x4 acc[16];
#pragma unroll
    for (int nt = 0; nt < 16; ++nt)
#pragma unroll
        for (int j = 0; j < 4; ++j) acc[nt][j] = 0.0f;
    const u16* ap = A + (size_t)(rowb + (lane & 15)) * K1 + ((lane >> 4) << 3);
    const s16x8* bp = (const s16x8*)W1p + lane;
#pragma unroll
    for (int ks = 0; ks < K1 / 32; ++ks) {
        s16x8 a = *(const s16x8*)(ap + ks * 32);
#pragma unroll
        for (int nt = 0; nt < 16; ++nt) {
            s16x8 b = bp[(size_t)(ks * 16 + nt) * 64];
            acc[nt] = __builtin_amdgcn_mfma_f32_16x16x32_bf16(a, b, acc[nt], 0, 0, 0);
        }
    }
    int g = lane >> 4, cb = lane & 15;
#pragma unroll
    for (int nt = 0; nt < 16; ++nt) {
        int c = nt * 16 + cb;
        float bi = b1[c];
#pragma unroll
        for (int j = 0; j < 4; ++j) {
            int r = wave * 16 + g * 4 + j;   // local row
            hlds[(size_t)r * HPITCH + c] = f2bf(fmaxf(acc[nt][j] + bi, 0.0f));
        }
    }
    // NOTE: no barrier needed before fc2 — each wave reads back only its own 16 rows.
}

// fc2: hlds (K=256) @ W2p (packed, C=128) -> acc[8]
__device__ __forceinline__ void mlp_fc2(const u16* __restrict__ hlds, const u16* __restrict__ W2p,
                                        int lane, int wave, f32x4* acc) {
    const u16* ap = hlds + (size_t)(wave * 16 + (lane & 15)) * HPITCH + ((lane >> 4) << 3);
    const s16x8* bp = (const s16x8*)W2p + lane;
#pragma unroll
    for (int ks = 0; ks < 8; ++ks) {
        s16x8 a = *(const s16x8*)(ap + ks * 32);
#pragma unroll
        for (int nt = 0; nt < 8; ++nt) {
            s16x8 b = bp[(size_t)(ks * 8 + nt) * 64];
            acc[nt] = __builtin_amdgcn_mfma_f32_16x16x32_bf16(a, b, acc[nt], 0, 0, 0);
        }
    }
}

// ---------- mlp1: cat1 -> h(LDS) -> xnew (+bpack for edges, +column partials) ----------
__global__ __launch_bounds__(256) void k_mlp1(const u16* __restrict__ cat, const u16* __restrict__ W1p,
                                              const float* __restrict__ b1v, const u16* __restrict__ W2p,
                                              const float* __restrict__ b2v, const float* __restrict__ xv,
                                              const float* __restrict__ xe, float* __restrict__ xnew,
                                              u16* __restrict__ bpack, float* __restrict__ part) {
    __shared__ u16 hlds[64 * HPITCH];
    __shared__ float shsum[4 * 128];
    int t = threadIdx.x, lane = t & 63, wave = t >> 6;
    int rowb_blk = blockIdx.x * 64;
    mlp_fc1<256>(cat, W1p, b1v, rowb_blk, lane, wave, hlds);
    f32x4 acc[8];
#pragma unroll
    for (int nt = 0; nt < 8; ++nt)
#pragma unroll
        for (int j = 0; j < 4; ++j) acc[nt][j] = 0.0f;
    mlp_fc2(hlds, W2p, lane, wave, acc);
    int g = lane >> 4, cb = lane & 15;
    int r0 = rowb_blk + wave * 16 + g * 4;
    bool isE = (r0 >= NV);
    int e0 = r0 - NV;
    float colpart[8];
#pragma unroll
    for (int nt = 0; nt < 8; ++nt) {
        int c = nt * 16 + cb;
        float bi = b2v[c];
        float vv[4];
        float cs = 0.0f;
#pragma unroll
        for (int j = 0; j < 4; ++j) {
            int r = r0 + j;
            float res = isE ? xe[(size_t)(r - NV) * DD + c] : xv[(size_t)r * DD + c];
            vv[j] = acc[nt][j] + bi + res;
            xnew[(size_t)r * DD + c] = vv[j];
            cs += vv[j];
        }
        colpart[nt] = cs;
        if (isE) {
            ushort4 p;
            p.x = f2bf(vv[0]); p.y = f2bf(vv[1]); p.z = f2bf(vv[2]); p.w = f2bf(vv[3]);
            size_t o = (((size_t)(e0 >> 5) * 8 + nt) * 64 + cb + (((e0 & 31) >> 3) << 4)) * 8 + (e0 & 7);
            *(ushort4*)(bpack + o) = p;
        }
    }
#pragma unroll
    for (int nt = 0; nt < 8; ++nt) {
        colpart[nt] += __shfl_xor(colpart[nt], 16, 64);
        colpart[nt] += __shfl_xor(colpart[nt], 32, 64);
    }
    if (lane < 16) {
#pragma unroll
        for (int nt = 0; nt < 8; ++nt) shsum[wave * 128 + nt * 16 + lane] = colpart[nt];
    }
    __syncthreads();
    if (t < 128) part[(size_t)blockIdx.x * 128 + t] = shsum[t] + shsum[128 + t] + shsum[256 + t] + shsum[384 + t];
}

// ---------- big GEMM: BM=64, split-K=8, 1024 blocks (4/CU) ----------
__global__ __launch_bounds__(256, 4) void k_big(const float* __restrict__ inc, const u16* __restrict__ bpack,
                                                float* __restrict__ yp) {
    __shared__ u16 aT[64 * 72];      // 9 KB
    __shared__ u16 bT[1024 * 8];     // 16 KB
    int t = threadIdx.x;
    int lane = t & 63, w = t >> 6;
    int row0 = blockIdx.x * 64;
    int split = blockIdx.y;
    int kbase = split * KRANGE;
    const int sr = t >> 4;
    const int sc = (t & 15) * 4;

    f32x4 ar[4];
    s16x8 br[4];
    f32x4 acc[8];
#pragma unroll
    for (int nt = 0; nt < 8; ++nt)
#pragma unroll
        for (int j = 0; j < 4; ++j) acc[nt][j] = 0.0f;

    {
        int k0 = kbase;
#pragma unroll
        for (int i = 0; i < 4; ++i)
            ar[i] = ntload4(inc + (size_t)(row0 + i * 16 + sr) * NE + k0 + sc);
        const s16x8* src = (const s16x8*)bpack + (size_t)(k0 >> 5) * 512;
#pragma unroll
        for (int i = 0; i < 4; ++i) br[i] = src[i * 256 + t];
    }

    for (int step = 0; step < NSTEPB; ++step) {
        __syncthreads();
#pragma unroll
        for (int i = 0; i < 4; ++i) {
            ushort4 p;
            p.x = f2bf(ar[i][0]); p.y = f2bf(ar[i][1]); p.z = f2bf(ar[i][2]); p.w = f2bf(ar[i][3]);
            *(ushort4*)(aT + (size_t)(i * 16 + sr) * 72 + sc) = p;
        }
#pragma unroll
        for (int i = 0; i < 4; ++i)
            *(s16x8*)(bT + (size_t)(i * 256 + t) * 8) = br[i];
        __syncthreads();

        if (step + 1 < NSTEPB) {
            int k0 = kbase + (step + 1) * BKS;
#pragma unroll
            for (int i = 0; i < 4; ++i)
                ar[i] = ntload4(inc + (size_t)(row0 + i * 16 + sr) * NE + k0 + sc);
            const s16x8* src = (const s16x8*)bpack + (size_t)(k0 >> 5) * 512;
#pragma unroll
            for (int i = 0; i < 4; ++i) br[i] = src[i * 256 + t];
        }

        const u16* arow = aT + (size_t)(w * 16 + (lane & 15)) * 72 + ((lane >> 4) << 3);
#pragma unroll
        for (int kt = 0; kt < 2; ++kt) {
            s16x8 a = *(const s16x8*)(arow + kt * 32);
#pragma unroll
            for (int nt = 0; nt < 8; ++nt) {
                s16x8 b = *(const s16x8*)(bT + (size_t)((kt * 8 + nt) * 64 + lane) * 8);
                acc[nt] = __builtin_amdgcn_mfma_f32_16x16x32_bf16(a, b, acc[nt], 0, 0, 0);
            }
        }
    }

    int rb = row0 + w * 16 + ((lane >> 4) << 2);
    int cb = lane & 15;
#pragma unroll
    for (int nt = 0; nt < 8; ++nt)
#pragma unroll
        for (int j = 0; j < 4; ++j)
            yp[((size_t)split * NV + rb + j) * DD + nt * 16 + cb] = acc[nt][j];
}

// ---------- combine: x1 = (x_v_new + sum yp)/(1+suffix); LN -> cat2; block 0 also does x0 path ----------
__global__ __launch_bounds__(256) void k_combine(const float* __restrict__ xnewV, const float* __restrict__ yp,
                                                 const float* __restrict__ suffix, const float* __restrict__ pe2,
                                                 const float* __restrict__ g, const float* __restrict__ bn,
                                                 float* __restrict__ x1, u16* __restrict__ cat2,
                                                 const float* __restrict__ part,
                                                 const float* __restrict__ w1, const float* __restrict__ b1,
                                                 const float* __restrict__ w2, const float* __restrict__ b2,
                                                 float* __restrict__ x0n) {
    int wave = threadIdx.x >> 6, lane = threadIdx.x & 63;
    int row = blockIdx.x * 4 + wave;
    int c = lane * 2;
    float2 v = *(const float2*)(xnewV + (size_t)row * DD + c);
#pragma unroll
    for (int s = 0; s < BIGSPLIT; ++s) {
        float2 y = *(const float2*)(yp + ((size_t)s * NV + row) * DD + c);
        v.x += y.x; v.y += y.y;
    }
    float inv = 1.0f / (1.0f + suffix[row]);
    v.x *= inv; v.y *= inv;
    *(float2*)(x1 + (size_t)row * DD + c) = v;
    float mu = wsum(v.x + v.y) * (1.0f / DD);
    float var = wsum(v.x * v.x + v.y * v.y) * (1.0f / DD) - mu * mu;
    float rstd = rsqrtf(var + 1e-5f);
    u16* crow = cat2 + (size_t)row * 256;
    crow[c]     = f2bf((v.x - mu) * rstd * g[c]     + bn[c]);
    crow[c + 1] = f2bf((v.y - mu) * rstd * g[c + 1] + bn[c + 1]);
    const float* pr = pe2 + DD;
    crow[DD + c]     = f2bf(pr[c]);
    crow[DD + c + 1] = f2bf(pr[c + 1]);

    if (blockIdx.x == 0) {
        // x0 path overlapped with the other 2047 blocks
        __shared__ float x0s[128], cat0[256], h0[256], rs_[128], rq_[128];
        int t = threadIdx.x;
        if (t < 128) {
            float s = 0.0f;
            for (int p = 0; p < MTOT / 64; ++p) s += part[p * 128 + t];
            x0s[t] = s * (1.0f / MTOT);
            rs_[t] = x0s[t];
            rq_[t] = x0s[t] * x0s[t];
        }
        __syncthreads();
        for (int off = 64; off > 0; off >>= 1) {
            if (t < off) { rs_[t] += rs_[t + off]; rq_[t] += rq_[t + off]; }
            __syncthreads();
        }
        float mu0 = rs_[0] * (1.0f / DD);
        float var0 = rq_[0] * (1.0f / DD) - mu0 * mu0;
        float rstd0 = rsqrtf(var0 + 1e-5f);
        if (t < 128) {
            cat0[t] = (x0s[t] - mu0) * rstd0 * g[t] + bn[t];
            cat0[128 + t] = pe2[t];
        }
        __syncthreads();
        {
            float s = b1[t];
            for (int i = 0; i < 256; ++i) s += cat0[i] * w1[i * 256 + t];
            h0[t] = fmaxf(s, 0.0f);
        }
        __syncthreads();
        if (t < 128) {
            float y = b2[t];
            for (int j = 0; j < 256; ++j) y += h0[j] * w2[j * 128 + t];
            x0n[t] = x0s[t] + y;
        }
    }
}

// ---------- mlp2: cat2 -> h(LDS) -> xmid = x1 + mlp + x0n; fused LN3 -> a3 ----------
__global__ __launch_bounds__(256) void k_mlp2(const u16* __restrict__ cat2, const u16* __restrict__ W1p,
                                              const float* __restrict__ b1v, const u16* __restrict__ W2p,
                                              const float* __restrict__ b2v, const float* __restrict__ x1,
                                              const float* __restrict__ x0n, const float* __restrict__ g3,
                                              const float* __restrict__ b3n, float* __restrict__ xmid,
                                              u16* __restrict__ a3) {
    __shared__ u16 hlds[64 * HPITCH];
    int t = threadIdx.x, lane = t & 63, wave = t >> 6;
    int rowb_blk = blockIdx.x * 64;
    mlp_fc1<256>(cat2, W1p, b1v, rowb_blk, lane, wave, hlds);
    f32x4 acc[8];
#pragma unroll
    for (int nt = 0; nt < 8; ++nt)
#pragma unroll
        for (int j = 0; j < 4; ++j) acc[nt][j] = 0.0f;
    mlp_fc2(hlds, W2p, lane, wave, acc);
    int g = lane >> 4, cb = lane & 15;
    int r0 = rowb_blk + wave * 16 + g * 4;
    float vv[8][4];
    float g3v[8], b3v[8];
#pragma unroll
    for (int nt = 0; nt < 8; ++nt) {
        int c = nt * 16 + cb;
        float bi = b2v[c] + x0n[c];
        g3v[nt] = g3[c]; b3v[nt] = b3n[c];
#pragma unroll
        for (int j = 0; j < 4; ++j) {
            vv[nt][j] = acc[nt][j] + bi + x1[(size_t)(r0 + j) * DD + c];
            xmid[(size_t)(r0 + j) * DD + c] = vv[nt][j];
        }
    }
#pragma unroll
    for (int j = 0; j < 4; ++j) {
        float s1 = 0.0f, s2 = 0.0f;
#pragma unroll
        for (int nt = 0; nt < 8; ++nt) { s1 += vv[nt][j]; s2 += vv[nt][j] * vv[nt][j]; }
#pragma unroll
        for (int o = 1; o < 16; o <<= 1) {
            s1 += __shfl_xor(s1, o, 64);
            s2 += __shfl_xor(s2, o, 64);
        }
        float mu = s1 * (1.0f / DD);
        float var = s2 * (1.0f / DD) - mu * mu;
        float rstd = rsqrtf(var + 1e-5f);
#pragma unroll
        for (int nt = 0; nt < 8; ++nt) {
            int c = nt * 16 + cb;
            a3[(size_t)(r0 + j) * DD + c] = f2bf((vv[nt][j] - mu) * rstd * g3v[nt] + b3v[nt]);
        }
    }
}

// ---------- mlp3: a3 (K=128) -> h(LDS) -> out = xmid + mlp + bias_b ----------
__global__ __launch_bounds__(256) void k_mlp3(const u16* __restrict__ a3, const u16* __restrict__ W1p,
                                              const float* __restrict__ b1v, const u16* __restrict__ W2p,
                                              const float* __restrict__ b2v, const float* __restrict__ xmid,
                                              const float* __restrict__ bb, float* __restrict__ out) {
    __shared__ u16 hlds[64 * HPITCH];
    int t = threadIdx.x, lane = t & 63, wave = t >> 6;
    int rowb_blk = blockIdx.x * 64;
    mlp_fc1<128>(a3, W1p, b1v, rowb_blk, lane, wave, hlds);
    f32x4 acc[8];
#pragma unroll
    for (int nt = 0; nt < 8; ++nt)
#pragma unroll
        for (int j = 0; j < 4; ++j) acc[nt][j] = 0.0f;
    mlp_fc2(hlds, W2p, lane, wave, acc);
    int g = lane >> 4, cb = lane & 15;
    int r0 = rowb_blk + wave * 16 + g * 4;
#pragma unroll
    for (int nt = 0; nt < 8; ++nt) {
        int c = nt * 16 + cb;
        float bi = b2v[c] + bb[c];
#pragma unroll
        for (int j = 0; j < 4; ++j)
            out[(size_t)(r0 + j) * DD + c] = acc[nt][j] + bi + xmid[(size_t)(r0 + j) * DD + c];
    }
}

// ==================== launch ====================
extern "C" void kernel_launch(void* const* d_in, const int* in_sizes, int n_in,
                              void* d_out, int out_size, void* d_ws, size_t ws_size,
                              hipStream_t stream) {
    const float* x_v    = (const float*)d_in[0];
    const float* x_e    = (const float*)d_in[1];
    const float* inc    = (const float*)d_in[2];
    const float* suffix = (const float*)d_in[3];
    const int*   orders = (const int*)d_in[4];
    const float* m1w1 = (const float*)d_in[5];
    const float* m1b1 = (const float*)d_in[6];
    const float* m1w2 = (const float*)d_in[7];
    const float* m1b2 = (const float*)d_in[8];
    const float* m2w1 = (const float*)d_in[9];
    const float* m2b1 = (const float*)d_in[10];
    const float* m2w2 = (const float*)d_in[11];
    const float* m2b2 = (const float*)d_in[12];
    const float* m3w1 = (const float*)d_in[13];
    const float* m3b1 = (const float*)d_in[14];
    const float* m3w2 = (const float*)d_in[15];
    const float* m3b2 = (const float*)d_in[16];
    const float* g1 = (const float*)d_in[17];
    const float* b1n = (const float*)d_in[18];
    const float* g2 = (const float*)d_in[19];
    const float* b2n = (const float*)d_in[20];
    const float* g3 = (const float*)d_in[21];
    const float* b3n = (const float*)d_in[22];
    const float* bb = (const float*)d_in[23];
    float* out = (float*)d_out;

    char* w = (char*)d_ws;
    float* pe1   = (float*)(w + 0);
    float* pe2   = (float*)(w + 4608);
    float* x0n   = (float*)(w + 5632);
    float* part  = (float*)(w + 6144);        // 384*128*4 = 196608
    u16* w11t    = (u16*)(w + 202752);
    u16* w12t    = (u16*)(w + 333824);
    u16* w21t    = (u16*)(w + 399360);
    u16* w22t    = (u16*)(w + 530432);
    u16* w31t    = (u16*)(w + 595968);
    u16* w32t    = (u16*)(w + 661504);
    u16* cat1    = (u16*)(w + 1048576);       // 12.6 MB; cat2 aliases (cat1 dead after mlp1)
    u16* cat2    = (u16*)(w + 1048576);
    float* xnew  = (float*)(w + 13631488);    // 12.6 MB
    u16* bpack   = (u16*)(w + 26214400);      // 4.2 MB
    float* yp    = (float*)(w + 30408704);    // 33.5 MB
    float* x1    = (float*)(w + 63963136);    // 4.2 MB
    float* xmid  = (float*)(w + 68157440);    // 4.2 MB
    u16* a3      = (u16*)(w + 72351744);      // 2.1 MB -> end 74448896

    k_prep<<<1025, 256, 0, stream>>>(pe1, pe2, m1w1, w11t, m1w2, w12t,
                                     m2w1, w21t, m2w2, w22t, m3w1, w31t, m3w2, w32t);

    k_ln_cat1<<<MTOT / 4, 256, 0, stream>>>(x_v, x_e, orders, pe1, g1, b1n, cat1);
    k_mlp1<<<MTOT / 64, 256, 0, stream>>>(cat1, w11t, m1b1, w12t, m1b2, x_v, x_e, xnew, bpack, part);

    k_big<<<dim3(NV / 64, BIGSPLIT), 256, 0, stream>>>(inc, bpack, yp);

    k_combine<<<NV / 4, 256, 0, stream>>>(xnew, yp, suffix, pe2, g2, b2n, x1, cat2,
                                          part, m2w1, m2b1, m2w2, m2b2, x0n);

    k_mlp2<<<NV / 64, 256, 0, stream>>>(cat2, w21t, m2b1, w22t, m2b2, x1, x0n, g3, b3n, xmid, a3);
    k_mlp3<<<NV / 64, 256, 0, stream>>>(a3, w31t, m3b1, w32t, m3b2, xmid, bb, out);
}